// Round 13
// baseline (3288.217 us; speedup 1.0000x reference)
//
#include <hip/hip_runtime.h>
#include <hip/hip_bf16.h>
#include <stdint.h>

#define T_STEPS 1024
#define NH1 1024
#define NH2 512
#define D_IN 300
#define W1_LD 1324
#define W2_LD 1536
#define NVG 50000
#define NVS 25000
#define NTILE_G 391          // ceil(50000/128)
#define NTILE_S 196          // ceil(25000/128)
#define TPL (NTILE_G + NTILE_S)   // 587 tiles per m-level
#define NTILE (4 * TPL)           // 2348

typedef unsigned long long u64;
typedef __bf16 bf16x8 __attribute__((ext_vector_type(8)));
typedef short s16x8 __attribute__((ext_vector_type(8)));
typedef float f32x4 __attribute__((ext_vector_type(4)));

// ---------------------------------------------------------------------------
// Kernel 1: E[t][r] = b1[r] + sum_c W1[r][c] * X[idx[t]][c]   (c < 300)
// Block 0 zeroes all cross-block sync state each launch (replay hardening):
// ctl (64B) and buf1+buf2 (48KB contiguous).
// ---------------------------------------------------------------------------
__global__ __launch_bounds__(256) void e_kernel(
    const float* __restrict__ X,
    const float* __restrict__ W1,
    const float* __restrict__ b1,
    const int* __restrict__ idx,
    float* __restrict__ E,
    unsigned* __restrict__ ctl,
    u64* __restrict__ bufz)        // buf1 base; buf1+buf2 contiguous 6144 u64
{
  if (blockIdx.x == 0) {
    for (int i = threadIdx.x; i < 6144; i += 256) bufz[i] = 0ull;
    if (threadIdx.x < 16) ctl[threadIdx.x] = 0u;
  }

  __shared__ float Xs[32 * 300];
  const int rb = blockIdx.x & 7;
  const int tb = blockIdx.x >> 3;
  const int r0 = rb * 128;
  const int t0 = tb * 32;

  for (int t = 0; t < 32; ++t) {
    int node = idx[t0 + t];
    for (int c = threadIdx.x; c < 300; c += 256)
      Xs[t * 300 + c] = X[(size_t)node * D_IN + c];
  }
  __syncthreads();

  const int rl = threadIdx.x & 127;
  const int th = threadIdx.x >> 7;
  const int tbase = th * 16;
  const int r = r0 + rl;

  float acc[16];
  const float bias = b1[r];
#pragma unroll
  for (int tt = 0; tt < 16; ++tt) acc[tt] = bias;

  const float* wrow = W1 + (size_t)r * W1_LD;
  for (int c0 = 0; c0 < 300; c0 += 4) {
    float w0 = wrow[c0 + 0];
    float w1 = wrow[c0 + 1];
    float w2 = wrow[c0 + 2];
    float w3 = wrow[c0 + 3];
#pragma unroll
    for (int tt = 0; tt < 16; ++tt) {
      const float* xr = Xs + (tbase + tt) * 300 + c0;
      acc[tt] += w0 * xr[0] + w1 * xr[1] + w2 * xr[2] + w3 * xr[3];
    }
  }
#pragma unroll
  for (int tt = 0; tt < 16; ++tt)
    E[(size_t)(t0 + tbase + tt) * NH1 + r] = acc[tt];
}

// ---------------------------------------------------------------------------
// Kernel 2: FUSED persistent RNN + GEMM workers (r13 = r10 base, decontended).
//
// vs r10 (PASSED, 2852us total):
//  * RNN h2s stores are `sc0 sc1` (write-through to MEMORY side, r2-proven):
//    h2s is then clean at the coherence point, so workers read A with PLAIN
//    loads (cacheable in their own XCD L2) instead of ~600MB of sc0-sc1
//    probes against the winning XCD's L2. Store-ack overlaps the next poll's
//    own sc0-sc1 RT inside the same vmcnt(0) -> ~free on the RNN chain.
//  * Tile gate thinned: lvls 0-2 = ONE thread polling ONE tag (buf2[0]).
//    Invariant (r10's own chain): tag T at entry 0 => wave0's step-T poll
//    passed => all waves stored h1(T) after their step-(T-1) vmcnt(0) =>
//    all h2s rows <= T-3 drained to memory. need = 256*(lvl+1)+4.
//    lvl 3 = wave-0 all-512-entry sentinel check (post-RNN, no contention).
//    Per-block done_lvl caching: one gate per level per block.
//  * buf1/buf2/ctl zeroed each launch (replay hardening).
// Copier/flag design of r11/r12 is ABANDONED (failed twice, cause unproven).
// ---------------------------------------------------------------------------
__global__ __launch_bounds__(512, 2) void rnn_kernel(
    const float* __restrict__ W1,
    const float* __restrict__ W2,
    const float* __restrict__ b2,
    const float* __restrict__ E,
    u64* __restrict__ buf1,     // [4][1024]
    u64* __restrict__ buf2,     // [4][512]
    __hip_bfloat16* __restrict__ h2s,   // [T][512]
    unsigned* __restrict__ ctl,         // [8] cnt, [8] winner, [9] tile ctr
    const float* __restrict__ Wg,
    const float* __restrict__ bg,
    const float* __restrict__ Ws,
    const float* __restrict__ bs,
    float* __restrict__ out)
{
  __shared__ float lds1[2][NH1];
  __shared__ float lds2[2][NH2];
  __shared__ short As[256 * 64];
  __shared__ short Bs[128 * 64];
  __shared__ int s_role;
  __shared__ unsigned s_tile;

  // ---- election ----
  if (threadIdx.x == 0) {
    int xcd;
    asm volatile("s_getreg_b32 %0, hwreg(HW_REG_XCC_ID)" : "=s"(xcd));
    xcd &= 7;
    unsigned rk = atomicAdd(&ctl[xcd], 1u);
    unsigned wnr;
    while ((wnr = __hip_atomic_load(&ctl[8], __ATOMIC_RELAXED,
                                    __HIP_MEMORY_SCOPE_AGENT)) == 0u) {
      if (rk == 31u) {
        atomicCAS(&ctl[8], 0u, (unsigned)(xcd + 1));
      } else {
        __builtin_amdgcn_s_sleep(16);
      }
    }
    int role;
    if (wnr == (unsigned)(xcd + 1))
      role = (rk < 32u) ? (int)rk : -2;   // winner : exit (winning XCD)
    else
      role = -1;                          // worker
    s_role = role;
  }
  __syncthreads();
  const int role = s_role;
  if (role == -2) return;

  const int tid = threadIdx.x;
  const int lane = tid & 63;

  if (role >= 0) {
    // ================= RNN path (r8 champion) =================
    const int b = role;                           // 0..31
    const int w = tid >> 6;                       // wave 0..7
    const int wvid = b * 8 + w;                   // 0..255
    const int r1 = wvid * 4;
    const int r2 = wvid * 2;
    const int oct = (w + b) & 7;

    float w1r[4][16];
#pragma unroll
    for (int i = 0; i < 4; ++i)
#pragma unroll
      for (int j = 0; j < 16; ++j)
        w1r[i][j] = W1[(size_t)(r1 + i) * W1_LD + D_IN + lane + 64 * j];

    float w2r[2][24];
#pragma unroll
    for (int i = 0; i < 2; ++i)
#pragma unroll
      for (int j = 0; j < 24; ++j)
        w2r[i][j] = W2[(size_t)(r2 + i) * W2_LD + lane + 64 * j];

    const float b2a = b2[r2];
    const float b2b = b2[r2 + 1];

    for (int s = 0; s <= T_STEPS; ++s) {
      float ev = 0.f;
      if (s < T_STEPS) ev = E[(size_t)s * NH1 + r1 + (lane & 3)];

      float v1[2] = {0.f, 0.f};
      float v2 = 0.f;
      unsigned miss = 0;
      if (s >= 1) miss |= 0x3u;
      if (s >= 2) miss |= 0x4u;
      const u64* p1 = buf1 + (size_t)(s & 3) * NH1 + 128 * oct + lane;
      const u64* p2 = buf2 + (size_t)((s - 1) & 3) * NH2 + 64 * oct + lane;
      const unsigned tag1 = (unsigned)s;
      const unsigned tag2 = (unsigned)(s - 1);

      while (miss) {
        u64 t1[2], t2;
        asm volatile(
            "global_load_dwordx2 %0, %3, off sc0 sc1\n\t"
            "global_load_dwordx2 %1, %3, off offset:512 sc0 sc1\n\t"
            "global_load_dwordx2 %2, %4, off sc0 sc1\n\t"
            "s_waitcnt vmcnt(0)"
            : "=&v"(t1[0]), "=&v"(t1[1]), "=&v"(t2)
            : "v"(p1), "v"(p2)
            : "memory");
#pragma unroll
        for (int j = 0; j < 2; ++j)
          if ((miss & (1u << j)) && (unsigned)(t1[j] >> 32) == tag1) {
            v1[j] = __uint_as_float((unsigned)t1[j]);
            miss &= ~(1u << j);
          }
        if ((miss & 0x4u) && (unsigned)(t2 >> 32) == tag2) {
          v2 = __uint_as_float((unsigned)t2);
          miss &= ~0x4u;
        }
      }

      const int pb = s & 1;
#pragma unroll
      for (int j = 0; j < 2; ++j) lds1[pb][128 * oct + 64 * j + lane] = v1[j];
      lds2[pb][64 * oct + lane] = v2;
      __syncthreads();

      float a0 = 0.f, a1 = 0.f, a2 = 0.f, a3 = 0.f, a4 = 0.f, a5 = 0.f;
#pragma unroll
      for (int j = 0; j < 16; ++j) {
        float h = lds1[pb][lane + 64 * j];
        a0 += w1r[0][j] * h;
        a1 += w1r[1][j] * h;
        a2 += w1r[2][j] * h;
        a3 += w1r[3][j] * h;
        a4 += w2r[0][j] * h;
        a5 += w2r[1][j] * h;
      }
#pragma unroll
      for (int j = 0; j < 8; ++j) {
        float h = lds2[pb][lane + 64 * j];
        a4 += w2r[0][16 + j] * h;
        a5 += w2r[1][16 + j] * h;
      }

#pragma unroll
      for (int off = 32; off; off >>= 1) {
        a0 += __shfl_xor(a0, off);
        a1 += __shfl_xor(a1, off);
        a2 += __shfl_xor(a2, off);
        a3 += __shfl_xor(a3, off);
      }
      if (s < T_STEPS && lane < 4) {
        float x = (lane == 0 ? a0 : lane == 1 ? a1 : lane == 2 ? a2 : a3) + ev;
        float h = x > 0.f ? x : 0.01f * x;
        u64 pk = ((u64)(unsigned)(s + 1) << 32) | (u64)__float_as_uint(h);
        u64* dst = buf1 + (size_t)((s + 1) & 3) * NH1 + r1 + lane;
        asm volatile("global_store_dwordx2 %0, %1, off sc0"
                     :: "v"(dst), "v"(pk) : "memory");
      }

      if (s >= 1) {
#pragma unroll
        for (int off = 32; off; off >>= 1) {
          a4 += __shfl_xor(a4, off);
          a5 += __shfl_xor(a5, off);
        }
        if (lane >= 4 && lane < 6) {
          int i = lane - 4;
          float x = (i == 0 ? a4 : a5) + (i == 0 ? b2a : b2b);
          float h = x > 0.f ? x : 0.01f * x;
          u64 pk = ((u64)(unsigned)s << 32) | (u64)__float_as_uint(h);
          u64* dst = buf2 + (size_t)(s & 3) * NH2 + r2 + i;
          asm volatile("global_store_dwordx2 %0, %1, off sc0"
                       :: "v"(dst), "v"(pk) : "memory");
          // h2s: write-through to MEMORY side so workers can plain-load it.
          __hip_bfloat16 hb = __float2bfloat16(h);
          unsigned hv = (unsigned)*reinterpret_cast<unsigned short*>(&hb);
          unsigned short* hdst =
              (unsigned short*)h2s + (size_t)(s - 1) * NH2 + r2 + i;
          asm volatile("global_store_short %0, %1, off sc0 sc1"
                       :: "v"(hdst), "v"(hv) : "memory");
        }
      }
    }

    // sentinel: prove ALL h2s stores drained, then release level-3 tiles.
    asm volatile("s_waitcnt vmcnt(0)" ::: "memory");
    if (lane >= 4 && lane < 6) {
      u64 pk = (u64)2048u << 32;
      u64* dst = buf2 + r2 + (lane - 4);   // slot 0
      asm volatile("global_store_dwordx2 %0, %1, off sc0"
                   :: "v"(dst), "v"(pk) : "memory");
    }
    return;
  }

  // ================= worker path: tile-stealing GEMM =================
  {
    const int wv = tid >> 6;
    const int wm = (wv & 1) * 128;
    const int wn = (wv >> 1) * 32;
    const int ml = lane & 15;
    const int kq = lane >> 4;
    const int arow = tid >> 3;           // 0..63
    const int kc = tid & 7;
    const int phys = kc ^ (arow & 7);
    int done_lvl = -1;

    for (;;) {
      if (tid == 0) s_tile = atomicAdd(&ctl[9], 1u);
      __syncthreads();
      const unsigned t = s_tile;
      if (t >= (unsigned)NTILE) break;
      const int lvl = (int)(t / (unsigned)TPL);
      const int rem = (int)(t - (unsigned)lvl * (unsigned)TPL);
      const int seg = rem >= NTILE_G;
      const int nb = seg ? rem - NTILE_G : rem;
      const int m0 = lvl * 256;
      const int n0 = nb * 128;
      const int N = seg ? NVS : NVG;
      const float* B = seg ? Ws : Wg;
      const float* bias = seg ? bs : bg;
      float* C = seg ? out + (size_t)1024 * NVG : out;

      // ---- progress gate (once per level per block) ----
      if (lvl > done_lvl) {
        if (lvl < 3) {
          // single-thread, single-tag gate (see header invariant)
          if (tid == 0) {
            const unsigned need = (unsigned)(256 * (lvl + 1) + 4);
            for (;;) {
              u64 v;
              asm volatile("global_load_dwordx2 %0, %1, off sc0 sc1\n\t"
                           "s_waitcnt vmcnt(0)"
                           : "=v"(v) : "v"(buf2) : "memory");
              unsigned tg = (unsigned)(v >> 32);
              if (tg >= need && tg <= 2048u) break;
              __builtin_amdgcn_s_sleep(32);
            }
          }
        } else {
          // lvl 3: all-wave sentinel check (post-RNN)
          if (tid < 64) {
            for (;;) {
              int ok = 1;
#pragma unroll
              for (int j = 0; j < 8; ++j) {
                u64 v;
                const u64* gp = buf2 + lane + 64 * j;
                asm volatile("global_load_dwordx2 %0, %1, off sc0 sc1\n\t"
                             "s_waitcnt vmcnt(0)"
                             : "=v"(v) : "v"(gp) : "memory");
                if ((unsigned)(v >> 32) != 2048u) ok = 0;
              }
              if (__all(ok)) break;
              __builtin_amdgcn_s_sleep(32);
            }
          }
        }
        __syncthreads();
        done_lvl = lvl;
      }

      f32x4 acc[8][2];
#pragma unroll
      for (int i = 0; i < 8; ++i)
#pragma unroll
        for (int j = 0; j < 2; ++j)
          acc[i][j] = (f32x4){0.f, 0.f, 0.f, 0.f};

      for (int kb = 0; kb < 512; kb += 64) {
        __syncthreads();
        // A: 4 x 16B PLAIN loads (h2s clean at memory; cacheable in own L2)
        const short* ab = (const short*)h2s + (size_t)(m0 + arow) * 512 + kb + kc * 8;
        s16x8 av0 = *(const s16x8*)(ab);
        s16x8 av1 = *(const s16x8*)(ab + 32768);
        s16x8 av2 = *(const s16x8*)(ab + 65536);
        s16x8 av3 = *(const s16x8*)(ab + 98304);
        // B: 2 rows (arow, arow+64), fp32 -> bf16
        int gr0 = n0 + arow;       if (gr0 >= N) gr0 = N - 1;
        int gr1 = n0 + 64 + arow;  if (gr1 >= N) gr1 = N - 1;
        const float* bp0 = B + (size_t)gr0 * 512 + kb + kc * 8;
        const float* bp1 = B + (size_t)gr1 * 512 + kb + kc * 8;
        f32x4 f00 = ((const f32x4*)bp0)[0], f01 = ((const f32x4*)bp0)[1];
        f32x4 f10 = ((const f32x4*)bp1)[0], f11 = ((const f32x4*)bp1)[1];
        bf16x8 bv0, bv1;
        bv0[0] = (__bf16)f00[0]; bv0[1] = (__bf16)f00[1];
        bv0[2] = (__bf16)f00[2]; bv0[3] = (__bf16)f00[3];
        bv0[4] = (__bf16)f01[0]; bv0[5] = (__bf16)f01[1];
        bv0[6] = (__bf16)f01[2]; bv0[7] = (__bf16)f01[3];
        bv1[0] = (__bf16)f10[0]; bv1[1] = (__bf16)f10[1];
        bv1[2] = (__bf16)f10[2]; bv1[3] = (__bf16)f10[3];
        bv1[4] = (__bf16)f11[0]; bv1[5] = (__bf16)f11[1];
        bv1[6] = (__bf16)f11[2]; bv1[7] = (__bf16)f11[3];
        *(s16x8*)(As + (arow +   0) * 64 + phys * 8) = av0;
        *(s16x8*)(As + (arow +  64) * 64 + phys * 8) = av1;
        *(s16x8*)(As + (arow + 128) * 64 + phys * 8) = av2;
        *(s16x8*)(As + (arow + 192) * 64 + phys * 8) = av3;
        *(bf16x8*)(Bs + (arow +  0) * 64 + phys * 8) = bv0;
        *(bf16x8*)(Bs + (arow + 64) * 64 + phys * 8) = bv1;
        __syncthreads();
#pragma unroll
        for (int ks = 0; ks < 2; ++ks) {
          bf16x8 af[8], bfr[2];
#pragma unroll
          for (int i = 0; i < 8; ++i) {
            int row = wm + 16 * i + ml;
            int pk2 = (ks * 4 + kq) ^ (row & 7);
            af[i] = *(const bf16x8*)(As + row * 64 + pk2 * 8);
          }
#pragma unroll
          for (int j = 0; j < 2; ++j) {
            int row = wn + 16 * j + ml;
            int pk2 = (ks * 4 + kq) ^ (row & 7);
            bfr[j] = *(const bf16x8*)(Bs + row * 64 + pk2 * 8);
          }
#pragma unroll
          for (int i = 0; i < 8; ++i)
#pragma unroll
            for (int j = 0; j < 2; ++j)
              acc[i][j] = __builtin_amdgcn_mfma_f32_16x16x32_bf16(
                  af[i], bfr[j], acc[i][j], 0, 0, 0);
        }
      }

      float bvv[2];
#pragma unroll
      for (int j = 0; j < 2; ++j) {
        int n = n0 + wn + 16 * j + ml;
        bvv[j] = (n < N) ? bias[n] : 0.f;
      }
#pragma unroll
      for (int i = 0; i < 8; ++i) {
        int mrow = m0 + wm + 16 * i + kq * 4;
#pragma unroll
        for (int j = 0; j < 2; ++j) {
          int n = n0 + wn + 16 * j + ml;
          if (n < N) {
#pragma unroll
            for (int r = 0; r < 4; ++r)
              C[(size_t)(mrow + r) * N + n] = acc[i][j][r] + bvv[j];
          }
        }
      }
    }
  }
}

// ---------------------------------------------------------------------------
// Kernel 4: in-place fp32 log-softmax per (row, segment).
// 2-pass online-LSE, f32x4 vectorized, 512 threads (r9, kept).
// ---------------------------------------------------------------------------
__global__ __launch_bounds__(512) void norm_kernel(float* __restrict__ out)
{
  const int b = blockIdx.x;
  const int t = b & 1023;
  const int seg = b >> 10;
  const size_t base = seg == 0 ? (size_t)t * NVG
                               : (size_t)1024 * NVG + (size_t)t * NVS;
  const int len4 = (seg == 0 ? NVG : NVS) >> 2;
  f32x4* p = (f32x4*)(out + base);
  const int lane = threadIdx.x & 63;
  const int wv = threadIdx.x >> 6;
  __shared__ float redm[8], reds[8];

  float m = -3.0e38f, ssum = 0.f;
  for (int i = threadIdx.x; i < len4; i += 512) {
    f32x4 v = p[i];
    float vm = fmaxf(fmaxf(v[0], v[1]), fmaxf(v[2], v[3]));
    if (vm > m) { ssum *= expf(m - vm); m = vm; }
    ssum += expf(v[0] - m) + expf(v[1] - m) + expf(v[2] - m) + expf(v[3] - m);
  }
#pragma unroll
  for (int off = 32; off; off >>= 1) {
    float mo = __shfl_xor(m, off);
    float so = __shfl_xor(ssum, off);
    float mn = fmaxf(m, mo);
    ssum = ssum * expf(m - mn) + so * expf(mo - mn);
    m = mn;
  }
  if (lane == 0) { redm[wv] = m; reds[wv] = ssum; }
  __syncthreads();
  float M = redm[0], S = reds[0];
#pragma unroll
  for (int k = 1; k < 8; ++k) {
    float mo = redm[k], so = reds[k];
    float mn = fmaxf(M, mo);
    S = S * expf(M - mn) + so * expf(mo - mn);
    M = mn;
  }
  const float lse = M + logf(S);

  for (int i = threadIdx.x; i < len4; i += 512) {
    f32x4 v = p[i];
    v[0] -= lse; v[1] -= lse; v[2] -= lse; v[3] -= lse;
    p[i] = v;
  }
}

// ---------------------------------------------------------------------------
extern "C" void kernel_launch(void* const* d_in, const int* in_sizes, int n_in,
                              void* d_out, int out_size, void* d_ws, size_t ws_size,
                              hipStream_t stream) {
  const float* X  = (const float*)d_in[0];
  const float* W1 = (const float*)d_in[1];
  const float* b1 = (const float*)d_in[2];
  const float* W2 = (const float*)d_in[3];
  const float* b2 = (const float*)d_in[4];
  const float* Wg = (const float*)d_in[5];
  const float* bg = (const float*)d_in[6];
  const float* Ws = (const float*)d_in[7];
  const float* bs = (const float*)d_in[8];
  const int* idx = (const int*)d_in[9];
  float* out = (float*)d_out;

  char* ws = (char*)d_ws;
  float* E = (float*)ws;                                         // 4 MB
  __hip_bfloat16* h2s = (__hip_bfloat16*)(ws + (size_t)4194304); // 1 MB
  u64* buf1 = (u64*)(ws + (size_t)5242880);                      // 32 KB
  u64* buf2 = (u64*)(ws + (size_t)5275648);                      // 16 KB (contiguous after buf1)
  // Control block: tail 64B of `out` (written only by the LAST gemm tile).
  unsigned* ctl = (unsigned*)(out + (size_t)1024 * (NVG + NVS) - 16);

  e_kernel<<<256, 256, 0, stream>>>(X, W1, b1, idx, E, ctl, buf1);
  rnn_kernel<<<512, 512, 0, stream>>>(W1, W2, b2, E, buf1, buf2, h2s, ctl,
                                      Wg, bg, Ws, bs, out);
  norm_kernel<<<2048, 512, 0, stream>>>(out);
}